// Round 1
// 625.401 us; speedup vs baseline: 1.0100x; 1.0100x over previous
//
#include <hip/hip_runtime.h>

#define H 64
#define BSZ 16
#define SEQL 512
#define OUTD 2

#define TOKENS_PER_B (2 * SEQL)   // 1024 tokens contribute to each h[b]
#define CHUNKS 64                 // blocks per batch element
#define THREADS 256               // 4 waves per block
#define WAVES_PER_BLOCK 4
#define TOKENS_PER_WAVE (TOKENS_PER_B / (CHUNKS * WAVES_PER_BLOCK)) // 4

// Each wave processes TOKENS_PER_WAVE tokens of batch b.
// Per token: contrib[c] = sum_w sos[w] * E[tok][w*64+c]; accumulated over tokens.
// Lane layout: rg = lane>>4 (row group 0..3), c16 = lane&15 (float4 column).
// Pass p covers rows 4p..4p+3: wave reads float4s [p*64 .. p*64+63] -> one
// contiguous 1 KiB chunk per pass (16 B/lane, ideal coalescing).
//
// Output: each block writes its 64-float partial sum to its OWN slot in
// partials[BSZ*CHUNKS][H]. Every element is overwritten every call, so no
// zero-init of the workspace is needed (poison-safe) and there are no
// global atomics.
__global__ __launch_bounds__(THREADS) void gather_partial_kernel(
    const int* __restrict__ s1, const int* __restrict__ s2,
    const float* __restrict__ embed, const float* __restrict__ sos,
    float* __restrict__ partials /* [BSZ*CHUNKS][H] */)
{
    const int b     = blockIdx.x / CHUNKS;
    const int chunk = blockIdx.x % CHUNKS;
    const int wave  = threadIdx.x >> 6;
    const int lane  = threadIdx.x & 63;
    const int rg    = lane >> 4;        // row group within a pass
    const int c16   = lane & 15;        // float4 column index

    // Preload the 16 sos values this lane needs: row = p*4 + rg
    float sosr[16];
#pragma unroll
    for (int p = 0; p < 16; ++p) sosr[p] = sos[p * 4 + rg];

    float4 acc = make_float4(0.f, 0.f, 0.f, 0.f);

    const int t0 = chunk * (WAVES_PER_BLOCK * TOKENS_PER_WAVE) + wave * TOKENS_PER_WAVE;
#pragma unroll
    for (int ti = 0; ti < TOKENS_PER_WAVE; ++ti) {
        const int t_idx = t0 + ti;
        int tok;
        if (t_idx < SEQL) tok = s1[b * SEQL + t_idx];
        else              tok = s2[b * SEQL + (t_idx - SEQL)];

        const float4* __restrict__ row = (const float4*)(embed + (size_t)tok * (H * H));
#pragma unroll
        for (int p = 0; p < 16; ++p) {
            float4 v = row[p * 64 + rg * 16 + c16];
            const float s = sosr[p];
            acc.x = fmaf(s, v.x, acc.x);
            acc.y = fmaf(s, v.y, acc.y);
            acc.z = fmaf(s, v.z, acc.z);
            acc.w = fmaf(s, v.w, acc.w);
        }
    }

    // Reduce the 4 row-groups: lanes {l, l+16, l+32, l+48} hold same columns.
    acc.x += __shfl_down(acc.x, 32); acc.y += __shfl_down(acc.y, 32);
    acc.z += __shfl_down(acc.z, 32); acc.w += __shfl_down(acc.w, 32);
    acc.x += __shfl_down(acc.x, 16); acc.y += __shfl_down(acc.y, 16);
    acc.z += __shfl_down(acc.z, 16); acc.w += __shfl_down(acc.w, 16);

    // Cross-wave reduce via LDS (no atomics), then one coalesced 256 B store.
    __shared__ float hsum[WAVES_PER_BLOCK][H];
    if (lane < 16) {
        hsum[wave][c16 * 4 + 0] = acc.x;
        hsum[wave][c16 * 4 + 1] = acc.y;
        hsum[wave][c16 * 4 + 2] = acc.z;
        hsum[wave][c16 * 4 + 3] = acc.w;
    }
    __syncthreads();
    if (threadIdx.x < H) {
        const int i = threadIdx.x;
        const float s = hsum[0][i] + hsum[1][i] + hsum[2][i] + hsum[3][i];
        partials[(size_t)blockIdx.x * H + i] = s;
    }
}

// Reduce 64 partials per (b,i), then MLP: x = relu(h @ w1^T + b1); out = x @ w2^T + b2.
// One block, 1024 threads = (b, i). partials is 256 KB, freshly written -> L2-hot.
__global__ __launch_bounds__(BSZ * H) void reduce_mlp_kernel(
    const float* __restrict__ partials,
    const float* __restrict__ w1, const float* __restrict__ b1,
    const float* __restrict__ w2, const float* __restrict__ b2,
    float* __restrict__ out)
{
    __shared__ float hs[BSZ][H];
    __shared__ float xs[BSZ][H];
    const int tid = threadIdx.x;
    const int b = tid >> 6;
    const int i = tid & 63;

    // h[b][i] = sum over the 64 chunk-partials. Wave lanes read contiguous
    // 256 B per (b,chunk) -> coalesced.
    float hv = 0.0f;
#pragma unroll
    for (int c = 0; c < CHUNKS; ++c)
        hv += partials[((size_t)(b * CHUNKS + c)) * H + i];
    hs[b][i] = hv;
    __syncthreads();

    // Layer 1: all lanes of a wave share b -> hs[b][j] reads are broadcasts.
    float sum = b1[i];
#pragma unroll
    for (int j = 0; j < H; ++j) sum = fmaf(hs[b][j], w1[i * H + j], sum);
    xs[b][i] = fmaxf(sum, 0.0f);
    __syncthreads();

    // Layer 2: 32 outputs.
    if (tid < BSZ * OUTD) {
        const int bb = tid >> 1;
        const int o  = tid & 1;
        float s = b2[o];
#pragma unroll
        for (int j = 0; j < H; ++j) s = fmaf(xs[bb][j], w2[o * H + j], s);
        out[bb * OUTD + o] = s;
    }
}

extern "C" void kernel_launch(void* const* d_in, const int* in_sizes, int n_in,
                              void* d_out, int out_size, void* d_ws, size_t ws_size,
                              hipStream_t stream) {
    const int*   s1    = (const int*)  d_in[0];
    const int*   s2    = (const int*)  d_in[1];
    const float* embed = (const float*)d_in[2];
    const float* sos   = (const float*)d_in[3];
    const float* w1    = (const float*)d_in[4];
    const float* b1    = (const float*)d_in[5];
    const float* w2    = (const float*)d_in[6];
    const float* b2    = (const float*)d_in[7];
    float*       out   = (float*)d_out;
    float*       partials = (float*)d_ws;   // [BSZ*CHUNKS][H] = 256 KB, fully overwritten

    gather_partial_kernel<<<BSZ * CHUNKS, THREADS, 0, stream>>>(s1, s2, embed, sos, partials);
    reduce_mlp_kernel<<<1, BSZ * H, 0, stream>>>(partials, w1, b1, w2, b2, out);
}